// Round 1
// baseline (136.331 us; speedup 1.0000x reference)
//
#include <hip/hip_runtime.h>
#include <hip/hip_bf16.h>

#define N_PED 1024
#define H 128
#define G 8
#define NCELL 64
#define K_TOT 8192
#define HALF_NB 16.0f
#define INV_CELL 0.25f

__device__ __forceinline__ unsigned map_f2u(float v) {
    unsigned u = __float_as_uint(v);
    return (u & 0x80000000u) ? ~u : (u | 0x80000000u);
}
__device__ __forceinline__ float unmap_u2f(unsigned u) {
    return __uint_as_float((u & 0x80000000u) ? (u ^ 0x80000000u) : ~u);
}

// One block per pedestrian i. Builds the 64x128 max-pooled grid in LDS,
// writes it to ws as fp32 [N_PED][K_TOT].
__global__ __launch_bounds__(128) void build_grid(const float* __restrict__ hs,
                                                  const float* __restrict__ pos,
                                                  float* __restrict__ grid) {
    __shared__ unsigned lgrid[NCELL * H];   // 32 KB, float-as-mapped-uint
    __shared__ int      list[N_PED];        // 4 KB, packed (j<<8)|cell
    __shared__ int      cnt;

    const int i   = blockIdx.x;
    const int tid = threadIdx.x;

    const unsigned init_u = 0x80000000u;    // map_f2u(0.0f)
    for (int k = tid; k < NCELL * H; k += 128) lgrid[k] = init_u;
    if (tid == 0) cnt = 0;
    __syncthreads();

    const float2 pi = ((const float2*)pos)[i];

    // phase 1: classify all candidate neighbors, compact valid ones
    for (int j = tid; j < N_PED; j += 128) {
        float2 pj = ((const float2*)pos)[j];
        float rx = pj.x - pi.x;
        float ry = pj.y - pi.y;
        if (j != i && fabsf(rx) <= HALF_NB && fabsf(ry) <= HALF_NB) {
            int gx = (int)floorf((rx + HALF_NB) * INV_CELL);
            int gy = (int)floorf((ry + HALF_NB) * INV_CELL);
            gx = min(G - 1, max(0, gx));
            gy = min(G - 1, max(0, gy));
            int cell = gy * G + gx;
            int slot = atomicAdd(&cnt, 1);
            list[slot] = (j << 8) | cell;
        }
    }
    __syncthreads();

    // phase 2: thread tid owns hidden dim tid; LDS atomicMax (order-free)
    const int n = cnt;
    for (int e = 0; e < n; ++e) {
        int packed = list[e];
        int j    = packed >> 8;
        int cell = packed & 255;
        float v = hs[(size_t)j * H + tid];
        atomicMax(&lgrid[cell * H + tid], map_f2u(v));
    }
    __syncthreads();

    // phase 3: unmap and write out (coalesced)
    float* dst = grid + (size_t)i * K_TOT;
    for (int k = tid; k < K_TOT; k += 128) dst[k] = unmap_u2f(lgrid[k]);
}

// out[i][o] = b[o]
__global__ __launch_bounds__(256) void init_out(const float* __restrict__ b,
                                                float* __restrict__ out) {
    int idx = blockIdx.x * 256 + threadIdx.x;   // 512 blocks * 256 = 131072
    out[idx] = b[idx & (H - 1)];
}

// Partial GEMM: A[N_PED][K_TOT] @ W[K_TOT][H], K split across blockIdx.y,
// fp32 atomicAdd into out.
__global__ __launch_bounds__(256) void gemm_partial(const float* __restrict__ A,
                                                    const float* __restrict__ Wm,
                                                    float* __restrict__ out) {
    constexpr int MT = 64;    // M tile
    constexpr int KC = 256;   // K chunk per block
    constexpr int TK = 32;    // K step per stage

    __shared__ float sA[TK][MT];   // 8 KB
    __shared__ float sW[TK][H];    // 16 KB

    const int m0  = blockIdx.x * MT;
    const int k0  = blockIdx.y * KC;
    const int tid = threadIdx.x;
    const int cg  = tid & 31;   // col group: cols cg*4 .. cg*4+3
    const int rgp = tid >> 5;   // row group: rows rgp*8 .. rgp*8+7

    float acc[8][4] = {};

    for (int kk = 0; kk < KC; kk += TK) {
        // stage A: 64 rows x 32 k (2048 floats, 8/thread), coalesced on k
        for (int x = tid; x < MT * TK; x += 256) {
            int r = x >> 5;
            int t = x & 31;
            sA[t][r] = A[(size_t)(m0 + r) * K_TOT + (k0 + kk + t)];
        }
        // stage W: 32 k x 128 cols (4096 floats, 16/thread), coalesced on col
        for (int x = tid; x < TK * H; x += 256) {
            int t  = x >> 7;
            int oo = x & 127;
            sW[t][oo] = Wm[(size_t)(k0 + kk + t) * H + oo];
        }
        __syncthreads();

        #pragma unroll
        for (int t = 0; t < TK; ++t) {
            float4 w  = *(const float4*)&sW[t][cg * 4];
            float4 a0 = *(const float4*)&sA[t][rgp * 8];
            float4 a1 = *(const float4*)&sA[t][rgp * 8 + 4];
            float ar[8] = {a0.x, a0.y, a0.z, a0.w, a1.x, a1.y, a1.z, a1.w};
            float wr[4] = {w.x, w.y, w.z, w.w};
            #pragma unroll
            for (int r = 0; r < 8; ++r)
                #pragma unroll
                for (int c = 0; c < 4; ++c)
                    acc[r][c] = fmaf(ar[r], wr[c], acc[r][c]);
        }
        __syncthreads();
    }

    #pragma unroll
    for (int r = 0; r < 8; ++r)
        #pragma unroll
        for (int c = 0; c < 4; ++c)
            atomicAdd(&out[(size_t)(m0 + rgp * 8 + r) * H + (cg * 4 + c)],
                      acc[r][c]);
}

extern "C" void kernel_launch(void* const* d_in, const int* in_sizes, int n_in,
                              void* d_out, int out_size, void* d_ws, size_t ws_size,
                              hipStream_t stream) {
    const float* hs  = (const float*)d_in[0];   // [1024][128]
    const float* pos = (const float*)d_in[1];   // [1024][2]
    const float* Wm  = (const float*)d_in[2];   // [8192][128]
    const float* b   = (const float*)d_in[3];   // [128]
    float* out  = (float*)d_out;                // [1024][128]
    float* grid = (float*)d_ws;                 // 32 MB fp32 scratch

    build_grid<<<N_PED, 128, 0, stream>>>(hs, pos, grid);
    init_out<<<(N_PED * H) / 256, 256, 0, stream>>>(b, out);
    gemm_partial<<<dim3(N_PED / 64, K_TOT / 256), 256, 0, stream>>>(grid, Wm, out);
}

// Round 2
// 53.111 us; speedup vs baseline: 2.5669x; 2.5669x over previous
//
#include <hip/hip_runtime.h>
#include <hip/hip_bf16.h>

#define N_PED 1024
#define H 128
#define G 8
#define NCELL 64
#define K_TOT 8192
#define HALF_NB 16.0f
#define INV_CELL 0.25f

#define KSPLIT 16
#define KC 512
#define BM 64
#define BK 64
#define PAD 8   // ushorts -> 144B row stride: fragment reads are 2-way (free)

typedef __attribute__((ext_vector_type(8))) short bf16x8;
typedef __attribute__((ext_vector_type(4))) float f32x4;

__device__ __forceinline__ unsigned map_f2u(float v) {
    unsigned u = __float_as_uint(v);
    return (u & 0x80000000u) ? ~u : (u | 0x80000000u);
}
__device__ __forceinline__ float unmap_u2f(unsigned u) {
    return __uint_as_float((u & 0x80000000u) ? (u ^ 0x80000000u) : ~u);
}
__device__ __forceinline__ ushort f2bf(float f) {   // round-to-nearest-even
    unsigned u = __float_as_uint(f);
    return (ushort)((u + 0x7FFFu + ((u >> 16) & 1u)) >> 16);
}

// One block per pedestrian i. Max-pool neighbors into 64x128 grid (LDS),
// write bf16 grid row [8192] to ws.
__global__ __launch_bounds__(128) void build_grid(const float* __restrict__ hs,
                                                  const float* __restrict__ pos,
                                                  ushort* __restrict__ grid) {
    __shared__ unsigned lgrid[NCELL * H];   // 32 KB mapped-uint fp32
    __shared__ int      list[N_PED];
    __shared__ int      cnt;

    const int i   = blockIdx.x;
    const int tid = threadIdx.x;

    const unsigned init_u = 0x80000000u;    // map_f2u(0.0f) -> empty/clamp at 0
    for (int k = tid; k < NCELL * H; k += 128) lgrid[k] = init_u;
    if (tid == 0) cnt = 0;
    __syncthreads();

    const float2 pi = ((const float2*)pos)[i];

    for (int j = tid; j < N_PED; j += 128) {
        float2 pj = ((const float2*)pos)[j];
        float rx = pj.x - pi.x;
        float ry = pj.y - pi.y;
        if (j != i && fabsf(rx) <= HALF_NB && fabsf(ry) <= HALF_NB) {
            int gx = (int)floorf((rx + HALF_NB) * INV_CELL);
            int gy = (int)floorf((ry + HALF_NB) * INV_CELL);
            gx = min(G - 1, max(0, gx));
            gy = min(G - 1, max(0, gy));
            int slot = atomicAdd(&cnt, 1);
            list[slot] = (j << 8) | (gy * G + gx);
        }
    }
    __syncthreads();

    const int n = cnt;
    for (int e = 0; e < n; ++e) {
        int packed = list[e];
        int j    = packed >> 8;
        int cell = packed & 255;
        float v = hs[(size_t)j * H + tid];
        atomicMax(&lgrid[cell * H + tid], map_f2u(v));
    }
    __syncthreads();

    ushort* dst = grid + (size_t)i * K_TOT;
    for (int k2 = tid; k2 < K_TOT / 2; k2 += 128) {
        ushort2 p;
        p.x = f2bf(unmap_u2f(lgrid[2 * k2]));
        p.y = f2bf(unmap_u2f(lgrid[2 * k2 + 1]));
        *(ushort2*)&dst[2 * k2] = p;
    }
}

// W [8192][128] fp32 -> Wt [128][8192] bf16 (transpose+convert via LDS tile)
__global__ __launch_bounds__(256) void wconv(const float* __restrict__ W,
                                             ushort* __restrict__ Wt) {
    __shared__ float tile[64][129];
    const int k0  = blockIdx.x * 64;
    const int tid = threadIdx.x;

    for (int x = tid; x < 64 * 128; x += 256) {
        int r = x >> 7, c = x & 127;
        tile[r][c] = W[(size_t)(k0 + r) * H + c];
    }
    __syncthreads();

    const int col = tid >> 1;          // 0..127
    const int kh  = (tid & 1) * 32;    // 0 or 32
    ushort tmp[32];
    #pragma unroll
    for (int k = 0; k < 32; ++k) tmp[k] = f2bf(tile[kh + k][col]);
    #pragma unroll
    for (int v = 0; v < 4; ++v)
        *(bf16x8*)&Wt[(size_t)col * K_TOT + k0 + kh + v * 8] =
            *(bf16x8*)&tmp[v * 8];
}

// A[1024][8192] bf16 @ Wt[128][8192] bf16 -> partial fp32 [KSPLIT][1024][128]
__global__ __launch_bounds__(256) void gemm_mfma(const ushort* __restrict__ A,
                                                 const ushort* __restrict__ Wt,
                                                 float* __restrict__ part) {
    __shared__ ushort sA[BM][BK + PAD];    // 64 x 72 x2B = 9.2 KB
    __shared__ ushort sB[H][BK + PAD];     // 128 x 72 x2B = 18.4 KB

    const int m0   = blockIdx.x * BM;
    const int k0   = blockIdx.y * KC;
    const int tid  = threadIdx.x;
    const int wave = tid >> 6;
    const int lane = tid & 63;
    const int ll   = lane & 15;
    const int lh   = lane >> 4;

    f32x4 acc[4][2] = {};   // [mtile][ntile]

    for (int kk = 0; kk < KC; kk += BK) {
        {   // stage A: 64 rows x 64 k, 32B/thread
            int r = tid >> 2;
            int c = (tid & 3) * 16;
            const ushort* src = A + (size_t)(m0 + r) * K_TOT + k0 + kk + c;
            *(bf16x8*)&sA[r][c]     = *(const bf16x8*)src;
            *(bf16x8*)&sA[r][c + 8] = *(const bf16x8*)(src + 8);
        }
        {   // stage B: 128 cols x 64 k, 64B/thread
            int c0 = tid >> 1;
            int kf = (tid & 1) * 32;
            const ushort* src = Wt + (size_t)c0 * K_TOT + k0 + kk + kf;
            *(bf16x8*)&sB[c0][kf]      = *(const bf16x8*)src;
            *(bf16x8*)&sB[c0][kf + 8]  = *(const bf16x8*)(src + 8);
            *(bf16x8*)&sB[c0][kf + 16] = *(const bf16x8*)(src + 16);
            *(bf16x8*)&sB[c0][kf + 24] = *(const bf16x8*)(src + 24);
        }
        __syncthreads();

        #pragma unroll
        for (int ks = 0; ks < 2; ++ks) {
            const int kb = ks * 32 + lh * 8;
            bf16x8 bfrag[2];
            #pragma unroll
            for (int nt = 0; nt < 2; ++nt)
                bfrag[nt] = *(const bf16x8*)&sB[wave * 32 + nt * 16 + ll][kb];
            #pragma unroll
            for (int mt = 0; mt < 4; ++mt) {
                bf16x8 afrag = *(const bf16x8*)&sA[mt * 16 + ll][kb];
                acc[mt][0] = __builtin_amdgcn_mfma_f32_16x16x32_bf16(
                    afrag, bfrag[0], acc[mt][0], 0, 0, 0);
                acc[mt][1] = __builtin_amdgcn_mfma_f32_16x16x32_bf16(
                    afrag, bfrag[1], acc[mt][1], 0, 0, 0);
            }
        }
        __syncthreads();
    }

    // D layout: col = lane&15, row = (lane>>4)*4 + reg   [measured m89/m91]
    float* dst = part + (size_t)blockIdx.y * (N_PED * H);
    #pragma unroll
    for (int mt = 0; mt < 4; ++mt)
        #pragma unroll
        for (int nt = 0; nt < 2; ++nt) {
            int col   = wave * 32 + nt * 16 + ll;
            int rbase = m0 + mt * 16 + lh * 4;
            #pragma unroll
            for (int r = 0; r < 4; ++r)
                dst[(size_t)(rbase + r) * H + col] = acc[mt][nt][r];
        }
}

// out = bias + sum over KSPLIT partials
__global__ __launch_bounds__(256) void reduce_out(const float* __restrict__ part,
                                                  const float* __restrict__ b,
                                                  float* __restrict__ out) {
    const int idx = (blockIdx.x * 256 + threadIdx.x) * 4;   // 128 blocks
    float4 acc = *(const float4*)&b[idx & (H - 1)];
    #pragma unroll
    for (int s = 0; s < KSPLIT; ++s) {
        float4 p = *(const float4*)&part[(size_t)s * (N_PED * H) + idx];
        acc.x += p.x; acc.y += p.y; acc.z += p.z; acc.w += p.w;
    }
    *(float4*)&out[idx] = acc;
}

extern "C" void kernel_launch(void* const* d_in, const int* in_sizes, int n_in,
                              void* d_out, int out_size, void* d_ws, size_t ws_size,
                              hipStream_t stream) {
    const float* hs  = (const float*)d_in[0];   // [1024][128]
    const float* pos = (const float*)d_in[1];   // [1024][2]
    const float* Wm  = (const float*)d_in[2];   // [8192][128]
    const float* b   = (const float*)d_in[3];   // [128]
    float* out = (float*)d_out;                 // [1024][128]

    ushort* grid = (ushort*)d_ws;                               // 16 MB
    ushort* Wt   = (ushort*)((char*)d_ws + (16u << 20));        // 2 MB
    float*  part = (float*)((char*)d_ws + (18u << 20));         // 8 MB

    build_grid<<<N_PED, 128, 0, stream>>>(hs, pos, grid);
    wconv<<<K_TOT / 64, 256, 0, stream>>>(Wm, Wt);
    gemm_mfma<<<dim3(N_PED / BM, KSPLIT), 256, 0, stream>>>(grid, Wt, part);
    reduce_out<<<(N_PED * H) / (256 * 4), 256, 0, stream>>>(part, b, out);
}

// Round 3
// 32.904 us; speedup vs baseline: 4.1433x; 1.6141x over previous
//
#include <hip/hip_runtime.h>
#include <hip/hip_bf16.h>

#define N_PED 1024
#define H 128
#define G 8
#define NCELL 64
#define K_TOT 8192
#define HALF_NB 16.0f
#define INV_CELL 0.25f

#define KSPLIT 16
#define KC 512          // K per block
#define BM 32
#define BK 64

typedef __attribute__((ext_vector_type(8))) short bf16x8;
typedef __attribute__((ext_vector_type(4))) float f32x4;

__device__ __forceinline__ unsigned map_f2u(float v) {
    unsigned u = __float_as_uint(v);
    return (u & 0x80000000u) ? ~u : (u | 0x80000000u);
}
__device__ __forceinline__ float unmap_u2f(unsigned u) {
    return __uint_as_float((u & 0x80000000u) ? (u ^ 0x80000000u) : ~u);
}
__device__ __forceinline__ ushort f2bf(float f) {   // round-to-nearest-even
    unsigned u = __float_as_uint(f);
    return (ushort)((u + 0x7FFFu + ((u >> 16) & 1u)) >> 16);
}
__device__ __forceinline__ void gl_lds16(const void* g, void* l) {
    __builtin_amdgcn_global_load_lds(
        (const __attribute__((address_space(1))) void*)g,
        (__attribute__((address_space(3))) void*)l, 16, 0, 0);
}

// blocks 0..1023: build pooled grid row (bf16 [8192]) for pedestrian i
// blocks 1024..1151: convert+transpose a 64-k slab of W into Wt bf16 [128][8192]
__global__ __launch_bounds__(512) void fused_pre(const float* __restrict__ hs,
                                                 const float* __restrict__ pos,
                                                 const float* __restrict__ W,
                                                 ushort* __restrict__ grid,
                                                 ushort* __restrict__ Wt) {
    __shared__ __align__(16) char smem[36872];
    const int tid = threadIdx.x;

    if (blockIdx.x < N_PED) {
        unsigned* lgrid = (unsigned*)smem;            // 32768 B
        int*      list  = (int*)(smem + 32768);       // 4096 B
        int*      cnt   = (int*)(smem + 36864);       // 4 B
        const int i = blockIdx.x;

        const unsigned iu = 0x80000000u;              // map_f2u(0.0f)
        uint4 iv = {iu, iu, iu, iu};
        for (int k = tid; k < NCELL * H / 4; k += 512) ((uint4*)lgrid)[k] = iv;
        if (tid == 0) *cnt = 0;
        __syncthreads();

        const float2 pi = ((const float2*)pos)[i];
        for (int j = tid; j < N_PED; j += 512) {
            float2 pj = ((const float2*)pos)[j];
            float rx = pj.x - pi.x;
            float ry = pj.y - pi.y;
            if (j != i && fabsf(rx) <= HALF_NB && fabsf(ry) <= HALF_NB) {
                int gx = (int)floorf((rx + HALF_NB) * INV_CELL);
                int gy = (int)floorf((ry + HALF_NB) * INV_CELL);
                gx = min(G - 1, max(0, gx));
                gy = min(G - 1, max(0, gy));
                int slot = atomicAdd(cnt, 1);
                list[slot] = (j << 8) | (gy * G + gx);
            }
        }
        __syncthreads();

        const int n   = *cnt;
        const int dim = tid & 127;
        const int eg  = tid >> 7;                     // 4-way neighbor parallel
        for (int e = eg; e < n; e += 4) {
            int packed = list[e];
            int j    = packed >> 8;
            int cell = packed & 255;
            float v = hs[j * H + dim];
            atomicMax(&lgrid[cell * H + dim], map_f2u(v));
        }
        __syncthreads();

        ushort* dst = grid + (size_t)i * K_TOT;
        for (int c = tid; c < K_TOT / 8; c += 512) {
            uint4 a = ((const uint4*)lgrid)[2 * c];
            uint4 b = ((const uint4*)lgrid)[2 * c + 1];
            ushort tmp[8];
            tmp[0] = f2bf(unmap_u2f(a.x)); tmp[1] = f2bf(unmap_u2f(a.y));
            tmp[2] = f2bf(unmap_u2f(a.z)); tmp[3] = f2bf(unmap_u2f(a.w));
            tmp[4] = f2bf(unmap_u2f(b.x)); tmp[5] = f2bf(unmap_u2f(b.y));
            tmp[6] = f2bf(unmap_u2f(b.z)); tmp[7] = f2bf(unmap_u2f(b.w));
            *(bf16x8*)&dst[8 * c] = *(const bf16x8*)tmp;
        }
    } else {
        float* tile = (float*)smem;                   // [64][129] = 33024 B
        const int bw  = blockIdx.x - N_PED;
        const int k0w = bw * 64;

        for (int x = tid; x < 64 * H; x += 512) {
            int r = x >> 7, c = x & 127;
            tile[r * 129 + c] = W[(size_t)(k0w + r) * H + c];
        }
        __syncthreads();

        const int col = tid >> 2;                     // 0..127
        const int kh  = (tid & 3) * 16;
        ushort tmp[16];
        #pragma unroll
        for (int t = 0; t < 16; ++t) tmp[t] = f2bf(tile[(kh + t) * 129 + col]);
        ushort* w0 = Wt + (size_t)col * K_TOT + k0w + kh;
        *(bf16x8*)w0       = *(const bf16x8*)&tmp[0];
        *(bf16x8*)(w0 + 8) = *(const bf16x8*)&tmp[8];
    }
}

// A[1024][8192] bf16 @ Wt[128][8192] bf16 -> partial fp32 [KSPLIT][1024][128]
// Staging: global_load_lds w16, linear LDS dest, XOR-swizzled source chunks,
// swizzled ds_read_b128 (rule #21: both-sides-or-neither).
__global__ __launch_bounds__(256) void gemm_mfma(const ushort* __restrict__ A,
                                                 const ushort* __restrict__ Wt,
                                                 float* __restrict__ part) {
    __shared__ ushort sA[BM * BK];   // 4 KB, chunk-swizzled rows of 8x16B
    __shared__ ushort sB[H * BK];    // 16 KB

    const int m0   = blockIdx.x * BM;
    const int k0   = blockIdx.y * KC;
    const int tid  = threadIdx.x;
    const int wave = tid >> 6;
    const int lane = tid & 63;
    const int ll   = lane & 15;
    const int lh   = lane >> 4;
    const int lr8  = lane >> 3;                 // 0..7 row-in-group
    const int cswz = (lane & 7) ^ (lr8 & 7);    // swizzled chunk to fetch

    f32x4 acc[2][2] = {};   // [mt][nt]

    for (int kk = 0; kk < KC; kk += BK) {
        const int kcol = k0 + kk;
        // A: wave w stages rows 8w..8w+7 (1KB)
        gl_lds16(A + (size_t)(m0 + 8 * wave + lr8) * K_TOT + kcol + cswz * 8,
                 &sA[8 * wave * BK]);
        // B: wave w stages rows 32w..32w+31 (4KB)
        #pragma unroll
        for (int t = 0; t < 4; ++t) {
            int br = 32 * wave + 8 * t;
            gl_lds16(Wt + (size_t)(br + lr8) * K_TOT + kcol + cswz * 8,
                     &sB[br * BK]);
        }
        __syncthreads();

        #pragma unroll
        for (int ks = 0; ks < 2; ++ks) {
            const int chunk = ks * 4 + lh;      // 16B chunk index (k = chunk*8)
            bf16x8 bfrag[2], afrag[2];
            #pragma unroll
            for (int nt = 0; nt < 2; ++nt) {
                int br = wave * 32 + nt * 16 + ll;
                bfrag[nt] = *(const bf16x8*)&sB[br * BK + ((chunk ^ (br & 7)) * 8)];
            }
            #pragma unroll
            for (int mt = 0; mt < 2; ++mt) {
                int ar = mt * 16 + ll;
                afrag[mt] = *(const bf16x8*)&sA[ar * BK + ((chunk ^ (ar & 7)) * 8)];
            }
            #pragma unroll
            for (int mt = 0; mt < 2; ++mt)
                #pragma unroll
                for (int nt = 0; nt < 2; ++nt)
                    acc[mt][nt] = __builtin_amdgcn_mfma_f32_16x16x32_bf16(
                        afrag[mt], bfrag[nt], acc[mt][nt], 0, 0, 0);
        }
        __syncthreads();
    }

    // D layout: col = lane&15, row = (lane>>4)*4 + reg   [m89/m91]
    float* dst = part + (size_t)blockIdx.y * (N_PED * H);
    #pragma unroll
    for (int mt = 0; mt < 2; ++mt)
        #pragma unroll
        for (int nt = 0; nt < 2; ++nt) {
            int col   = wave * 32 + nt * 16 + ll;
            int rbase = m0 + mt * 16 + lh * 4;
            #pragma unroll
            for (int r = 0; r < 4; ++r)
                dst[(size_t)(rbase + r) * H + col] = acc[mt][nt][r];
        }
}

// out = bias + sum over KSPLIT partials
__global__ __launch_bounds__(128) void reduce_out(const float* __restrict__ part,
                                                  const float* __restrict__ b,
                                                  float* __restrict__ out) {
    const int idx = (blockIdx.x * 128 + threadIdx.x) * 4;   // 256 blocks
    float4 acc = *(const float4*)&b[idx & (H - 1)];
    #pragma unroll
    for (int s = 0; s < KSPLIT; ++s) {
        float4 p = *(const float4*)&part[(size_t)s * (N_PED * H) + idx];
        acc.x += p.x; acc.y += p.y; acc.z += p.z; acc.w += p.w;
    }
    *(float4*)&out[idx] = acc;
}

extern "C" void kernel_launch(void* const* d_in, const int* in_sizes, int n_in,
                              void* d_out, int out_size, void* d_ws, size_t ws_size,
                              hipStream_t stream) {
    const float* hs  = (const float*)d_in[0];   // [1024][128]
    const float* pos = (const float*)d_in[1];   // [1024][2]
    const float* Wm  = (const float*)d_in[2];   // [8192][128]
    const float* b   = (const float*)d_in[3];   // [128]
    float* out = (float*)d_out;                 // [1024][128]

    ushort* grid = (ushort*)d_ws;                               // 16 MB
    ushort* Wt   = (ushort*)((char*)d_ws + (16u << 20));        // 2 MB
    float*  part = (float*)((char*)d_ws + (18u << 20));         // 8 MB

    fused_pre<<<N_PED + K_TOT / 64, 512, 0, stream>>>(hs, pos, Wm, grid, Wt);
    gemm_mfma<<<dim3(N_PED / BM, KSPLIT), 256, 0, stream>>>(grid, Wt, part);
    reduce_out<<<(N_PED * H) / (128 * 4), 128, 0, stream>>>(part, b, out);
}

// Round 4
// 30.172 us; speedup vs baseline: 4.5185x; 1.0905x over previous
//
#include <hip/hip_runtime.h>
#include <hip/hip_bf16.h>

#define N_PED 1024
#define H 128
#define G 8
#define NCELL 64
#define K_TOT 8192
#define HALF_NB 16.0f
#define INV_CELL 0.25f

#define KSPLIT 16
#define KC 512          // K per block
#define BM 32
#define BK 64
#define NSTAGE 8        // KC/BK

typedef __attribute__((ext_vector_type(8))) short bf16x8;
typedef __attribute__((ext_vector_type(4))) float f32x4;

__device__ __forceinline__ unsigned map_f2u(float v) {
    unsigned u = __float_as_uint(v);
    return (u & 0x80000000u) ? ~u : (u | 0x80000000u);
}
__device__ __forceinline__ float unmap_u2f(unsigned u) {
    return __uint_as_float((u & 0x80000000u) ? (u ^ 0x80000000u) : ~u);
}
__device__ __forceinline__ ushort f2bf(float f) {   // round-to-nearest-even
    unsigned u = __float_as_uint(f);
    return (ushort)((u + 0x7FFFu + ((u >> 16) & 1u)) >> 16);
}
__device__ __forceinline__ void gl_lds16(const void* g, void* l) {
    __builtin_amdgcn_global_load_lds(
        (const __attribute__((address_space(1))) void*)g,
        (__attribute__((address_space(3))) void*)l, 16, 0, 0);
}

// blocks 0..1023: build pooled grid row (bf16 [8192]) for pedestrian i
// blocks 1024..1151: convert+transpose a 64-k slab of W into Wt bf16 [128][8192]
__global__ __launch_bounds__(512) void fused_pre(const float* __restrict__ hs,
                                                 const float* __restrict__ pos,
                                                 const float* __restrict__ W,
                                                 ushort* __restrict__ grid,
                                                 ushort* __restrict__ Wt) {
    __shared__ __align__(16) char smem[36872];
    const int tid = threadIdx.x;

    if (blockIdx.x < N_PED) {
        unsigned* lgrid = (unsigned*)smem;            // 32768 B
        int*      list  = (int*)(smem + 32768);       // 4096 B
        int*      cnt   = (int*)(smem + 36864);       // 4 B
        const int i = blockIdx.x;

        const unsigned iu = 0x80000000u;              // map_f2u(0.0f)
        uint4 iv = {iu, iu, iu, iu};
        for (int k = tid; k < NCELL * H / 4; k += 512) ((uint4*)lgrid)[k] = iv;
        if (tid == 0) *cnt = 0;
        __syncthreads();

        const float2 pi = ((const float2*)pos)[i];
        for (int j = tid; j < N_PED; j += 512) {
            float2 pj = ((const float2*)pos)[j];
            float rx = pj.x - pi.x;
            float ry = pj.y - pi.y;
            if (j != i && fabsf(rx) <= HALF_NB && fabsf(ry) <= HALF_NB) {
                int gx = (int)floorf((rx + HALF_NB) * INV_CELL);
                int gy = (int)floorf((ry + HALF_NB) * INV_CELL);
                gx = min(G - 1, max(0, gx));
                gy = min(G - 1, max(0, gy));
                int slot = atomicAdd(cnt, 1);
                list[slot] = (j << 8) | (gy * G + gx);
            }
        }
        __syncthreads();

        // phase 2: 16-way entry parallel, 4 dims/thread, 2-deep prefetch
        const int n    = *cnt;
        const int dim4 = (tid & 31) * 4;
        const int eg   = tid >> 5;                    // 0..15
        int e  = eg;
        int p0 = (e < n) ? list[e] : -1;
        int p1 = (e + 16 < n) ? list[e + 16] : -1;
        float4 v0 = {};
        if (p0 >= 0) v0 = *(const float4*)&hs[(p0 >> 8) * H + dim4];
        while (p0 >= 0) {
            int p2 = (e + 32 < n) ? list[e + 32] : -1;
            float4 v1 = {};
            if (p1 >= 0) v1 = *(const float4*)&hs[(p1 >> 8) * H + dim4];
            unsigned* gph = &lgrid[(p0 & 255) * H + dim4];
            atomicMax(gph + 0, map_f2u(v0.x));
            atomicMax(gph + 1, map_f2u(v0.y));
            atomicMax(gph + 2, map_f2u(v0.z));
            atomicMax(gph + 3, map_f2u(v0.w));
            e += 16; p0 = p1; p1 = p2; v0 = v1;
        }
        __syncthreads();

        ushort* dst = grid + (size_t)i * K_TOT;
        for (int c = tid; c < K_TOT / 8; c += 512) {
            uint4 a = ((const uint4*)lgrid)[2 * c];
            uint4 b = ((const uint4*)lgrid)[2 * c + 1];
            ushort tmp[8];
            tmp[0] = f2bf(unmap_u2f(a.x)); tmp[1] = f2bf(unmap_u2f(a.y));
            tmp[2] = f2bf(unmap_u2f(a.z)); tmp[3] = f2bf(unmap_u2f(a.w));
            tmp[4] = f2bf(unmap_u2f(b.x)); tmp[5] = f2bf(unmap_u2f(b.y));
            tmp[6] = f2bf(unmap_u2f(b.z)); tmp[7] = f2bf(unmap_u2f(b.w));
            *(bf16x8*)&dst[8 * c] = *(const bf16x8*)tmp;
        }
    } else {
        float* tile = (float*)smem;                   // [64][129] = 33024 B
        const int bw  = blockIdx.x - N_PED;
        const int k0w = bw * 64;

        for (int x = tid; x < 64 * H; x += 512) {
            int r = x >> 7, c = x & 127;
            tile[r * 129 + c] = W[(size_t)(k0w + r) * H + c];
        }
        __syncthreads();

        const int col = tid >> 2;                     // 0..127
        const int kh  = (tid & 3) * 16;
        ushort tmp[16];
        #pragma unroll
        for (int t = 0; t < 16; ++t) tmp[t] = f2bf(tile[(kh + t) * 129 + col]);
        ushort* w0 = Wt + (size_t)col * K_TOT + k0w + kh;
        *(bf16x8*)w0       = *(const bf16x8*)&tmp[0];
        *(bf16x8*)(w0 + 8) = *(const bf16x8*)&tmp[8];
    }
}

// A[1024][8192] bf16 @ Wt[128][8192] bf16 -> partial fp32 [KSPLIT][1024][128]
// Triple-buffered LDS, counted vmcnt(5), raw s_barrier (T3/T4 minimum recipe).
// Staging: global_load_lds w16, linear LDS dest, XOR-swizzled source chunks,
// swizzled ds_read_b128 (rule #21: both-sides-or-neither).
__global__ __launch_bounds__(256) void gemm_mfma(const ushort* __restrict__ A,
                                                 const ushort* __restrict__ Wt,
                                                 float* __restrict__ part) {
    __shared__ ushort sA[3][BM * BK];   // 3 x 4 KB
    __shared__ ushort sB[3][H * BK];    // 3 x 16 KB

    const int m0   = blockIdx.x * BM;
    const int k0   = blockIdx.y * KC;
    const int tid  = threadIdx.x;
    const int wave = tid >> 6;
    const int lane = tid & 63;
    const int ll   = lane & 15;
    const int lh   = lane >> 4;
    const int lr8  = lane >> 3;                 // 0..7 row-in-group
    const int cswz = (lane & 7) ^ (lr8 & 7);    // swizzled chunk to fetch

    const ushort* Abase = A  + (size_t)(m0 + 8 * wave + lr8) * K_TOT + k0 + cswz * 8;
    const ushort* Bbase = Wt + (size_t)(32 * wave + lr8) * K_TOT      + k0 + cswz * 8;

    f32x4 acc[2][2] = {};   // [mt][nt]

#define STAGE(T, BUF)                                                        \
    do {                                                                     \
        gl_lds16(Abase + (T) * BK, &sA[BUF][8 * wave * BK]);                 \
        gl_lds16(Bbase + (T) * BK,                &sB[BUF][(32 * wave) * BK]);      \
        gl_lds16(Bbase + (T) * BK +  8 * K_TOT,   &sB[BUF][(32 * wave + 8) * BK]);  \
        gl_lds16(Bbase + (T) * BK + 16 * K_TOT,   &sB[BUF][(32 * wave + 16) * BK]); \
        gl_lds16(Bbase + (T) * BK + 24 * K_TOT,   &sB[BUF][(32 * wave + 24) * BK]); \
    } while (0)

    // prologue: stages 0,1 in flight; drain 0; barrier
    STAGE(0, 0);
    STAGE(1, 1);
    asm volatile("s_waitcnt vmcnt(5)" ::: "memory");
    __builtin_amdgcn_s_barrier();

    #pragma unroll
    for (int t = 0; t < NSTAGE; ++t) {
        if (t + 2 < NSTAGE) STAGE(t + 2, (t + 2) % 3);

        const int buf = t % 3;
        #pragma unroll
        for (int ks = 0; ks < 2; ++ks) {
            const int chunk = ks * 4 + lh;      // 16B chunk index (k = chunk*8)
            bf16x8 bfrag[2], afrag[2];
            #pragma unroll
            for (int nt = 0; nt < 2; ++nt) {
                int br = wave * 32 + nt * 16 + ll;
                bfrag[nt] = *(const bf16x8*)&sB[buf][br * BK + ((chunk ^ (br & 7)) * 8)];
            }
            #pragma unroll
            for (int mt = 0; mt < 2; ++mt) {
                int ar = mt * 16 + ll;
                afrag[mt] = *(const bf16x8*)&sA[buf][ar * BK + ((chunk ^ (ar & 7)) * 8)];
            }
            #pragma unroll
            for (int mt = 0; mt < 2; ++mt)
                #pragma unroll
                for (int nt = 0; nt < 2; ++nt)
                    acc[mt][nt] = __builtin_amdgcn_mfma_f32_16x16x32_bf16(
                        afrag[mt], bfrag[nt], acc[mt][nt], 0, 0, 0);
        }

        if (t + 1 < NSTAGE) {
            if (t + 2 < NSTAGE)
                asm volatile("s_waitcnt vmcnt(5)" ::: "memory");  // drain stage t+1
            else
                asm volatile("s_waitcnt vmcnt(0)" ::: "memory");  // last stage
            __builtin_amdgcn_s_barrier();
        }
    }
#undef STAGE

    // D layout: col = lane&15, row = (lane>>4)*4 + reg   [m89/m91]
    float* dst = part + (size_t)blockIdx.y * (N_PED * H);
    #pragma unroll
    for (int mt = 0; mt < 2; ++mt)
        #pragma unroll
        for (int nt = 0; nt < 2; ++nt) {
            int col   = wave * 32 + nt * 16 + ll;
            int rbase = m0 + mt * 16 + lh * 4;
            #pragma unroll
            for (int r = 0; r < 4; ++r)
                dst[(size_t)(rbase + r) * H + col] = acc[mt][nt][r];
        }
}

// out = bias + sum over KSPLIT partials
__global__ __launch_bounds__(128) void reduce_out(const float* __restrict__ part,
                                                  const float* __restrict__ b,
                                                  float* __restrict__ out) {
    const int idx = (blockIdx.x * 128 + threadIdx.x) * 4;   // 256 blocks
    float4 acc = *(const float4*)&b[idx & (H - 1)];
    #pragma unroll
    for (int s = 0; s < KSPLIT; ++s) {
        float4 p = *(const float4*)&part[(size_t)s * (N_PED * H) + idx];
        acc.x += p.x; acc.y += p.y; acc.z += p.z; acc.w += p.w;
    }
    *(float4*)&out[idx] = acc;
}

extern "C" void kernel_launch(void* const* d_in, const int* in_sizes, int n_in,
                              void* d_out, int out_size, void* d_ws, size_t ws_size,
                              hipStream_t stream) {
    const float* hs  = (const float*)d_in[0];   // [1024][128]
    const float* pos = (const float*)d_in[1];   // [1024][2]
    const float* Wm  = (const float*)d_in[2];   // [8192][128]
    const float* b   = (const float*)d_in[3];   // [128]
    float* out = (float*)d_out;                 // [1024][128]

    ushort* grid = (ushort*)d_ws;                               // 16 MB
    ushort* Wt   = (ushort*)((char*)d_ws + (16u << 20));        // 2 MB
    float*  part = (float*)((char*)d_ws + (18u << 20));         // 8 MB

    fused_pre<<<N_PED + K_TOT / 64, 512, 0, stream>>>(hs, pos, Wm, grid, Wt);
    gemm_mfma<<<dim3(N_PED / BM, KSPLIT), 256, 0, stream>>>(grid, Wt, part);
    reduce_out<<<(N_PED * H) / (128 * 4), 128, 0, stream>>>(part, b, out);
}